// Round 3
// baseline (10571.127 us; speedup 1.0000x reference)
//
#include <hip/hip_runtime.h>
#include <cstdint>
#include <cstddef>

typedef _Float16 h2_t __attribute__((ext_vector_type(2)));
typedef unsigned int uint;

#define BB 128
#define TT 512

// ---- ws layout (bytes) ----
#define OFF_PHH0 0          // 24*1024*16 = 393216
#define OFF_PHH1 393216     // 393216
#define OFF_PIH1 786432     // 393216
#define OFF_PIH0 1179648    // 12*1024*8 = 98304
#define OFF_PROG 1277952    // 128*4 -> pad 512
#define OFF_H2O  1278464    // 128*256*4 = 131072
#define OFF_H1G  1409536    // 128*512*128*4 = 33554432  (total 34963968)

__device__ __forceinline__ uint pack2(float a, float b){
  h2_t h; h.x = (_Float16)a; h.y = (_Float16)b;
  return __builtin_bit_cast(uint, h);
}
__device__ __forceinline__ float dot2(uint w, uint h, float acc){
  return __builtin_amdgcn_fdot2(__builtin_bit_cast(h2_t, w),
                                __builtin_bit_cast(h2_t, h), acc, false);
}
__device__ __forceinline__ float d16(uint4 w, uint4 h, float a){
  a = dot2(w.x,h.x,a); a = dot2(w.y,h.y,a);
  a = dot2(w.z,h.z,a); a = dot2(w.w,h.w,a);
  return a;
}
template<int CTRL>
__device__ __forceinline__ float dpp_addf(float x){
  int p = __builtin_amdgcn_update_dpp(0, __float_as_int(x), CTRL, 0xF, 0xF, true);
  return x + __int_as_float(p);
}
template<int CTRL>
__device__ __forceinline__ float dpp_movf(float x){
  return __int_as_float(__builtin_amdgcn_update_dpp(0, __float_as_int(x), CTRL, 0xF, 0xF, true));
}
template<int CTRL>
__device__ __forceinline__ uint dpp_movu(uint x){
  return (uint)__builtin_amdgcn_update_dpp(0, (int)x, CTRL, 0xF, 0xF, true);
}
// sum over each 16-lane row; result in ALL 16 lanes. Pure full-rate DPP row_ror
// (rotation butterfly: offsets {8,4,2,1} cover all 16 lanes regardless of direction).
__device__ __forceinline__ float red16(float x){
  x = dpp_addf<0x128>(x);   // row_ror:8
  x = dpp_addf<0x124>(x);   // row_ror:4
  x = dpp_addf<0x122>(x);   // row_ror:2
  x = dpp_addf<0x121>(x);   // row_ror:1
  return x;
}
__device__ __forceinline__ float sigf(float x){ return 1.0f/(1.0f+__expf(-x)); }
__device__ __forceinline__ float tanhf_(float x){
  x = fminf(15.0f, fmaxf(-15.0f, x));
  float e = __expf(2.0f*x);
  return (e-1.0f)/(e+1.0f);
}
__device__ __forceinline__ float pick4(float a0,float a1,float a2,float a3,int s){
  float x = (s&1)? a1:a0, y = (s&1)? a3:a2;
  return (s&2)? y:x;
}

// =================== prep: pack fp32 weights -> per-thread f16 images ===================
// Consumer org: tid in [0,1024): q=tid&15 (k-slice of 16), u=tid>>4 (units 4u..4u+3).
// K=256 images (PHH0/PHH1/PIH1): chunk c = (g*4+s)*2 + kk; uint4 elem e covers
// cols 16q+8kk+2e, +1 of row g*256+4u+s.   K=64 image (PIH0): uint2 per row r=g*4+s,
// elem e covers cols 4q+2e, +1.
__global__ void prep_kernel(const float* __restrict__ W_ih0, const float* __restrict__ W_hh0,
                            const float* __restrict__ W_ih1, const float* __restrict__ W_hh1,
                            uint* __restrict__ PHH0, uint* __restrict__ PHH1,
                            uint* __restrict__ PIH1, uint* __restrict__ PIH0)
{
  int i = blockIdx.x*256 + threadIdx.x;
  if (i < 294912) {
    const float* W; uint* dst;
    if (i < 98304)       { W = W_hh0; dst = PHH0; }
    else if (i < 196608) { W = W_hh1; dst = PHH1; i -= 98304; }
    else                 { W = W_ih1; dst = PIH1; i -= 196608; }
    int e = i&3, tid = (i>>2)&1023, c = i>>12;
    int q = tid&15, u = tid>>4;
    int r = c>>1, kk = c&1, g = r>>2, s = r&3;
    int row = g*256 + 4*u + s, col = 16*q + 8*kk + 2*e;
    dst[i] = pack2(W[row*256+col], W[row*256+col+1]);
  } else if (i < 319488) {
    int j = i - 294912;
    int e = j&1, tid = (j>>1)&1023, r = j>>11;
    int q = tid&15, u = tid>>4, g = r>>2, s = r&3;
    int row = g*256 + 4*u + s, col = 4*q + 2*e;
    PIH0[j] = pack2(W_ih0[row*64+col], W_ih0[row*64+col+1]);
  }
}

// =================== fused 2-layer pipelined GRU ===================
// blocks 0..127: layer0 (batch b); blocks 128..255: layer1 (batch b-128).
// All weights register-resident (f16, dot2 accumulation in fp32).
// One barrier per step; reduce is pure DPP; x prefetched a step ahead;
// layers coupled by device-scope release/acquire progress counters.
__global__ __launch_bounds__(1024) __attribute__((amdgpu_waves_per_eu(4,4)))
void gru_fused(const float* __restrict__ x,
               const uint4* __restrict__ PHH0, const uint2* __restrict__ PIH0,
               const uint4* __restrict__ PHH1, const uint4* __restrict__ PIH1,
               const float* __restrict__ b_ih0, const float* __restrict__ b_hh0,
               const float* __restrict__ b_ih1, const float* __restrict__ b_hh1,
               uint* __restrict__ h1g, float* __restrict__ h2o,
               int* __restrict__ prog)
{
  const int tid = threadIdx.x, q = tid & 15, u = tid >> 4, sl = q & 3;
  __shared__ __align__(16) uint hbuf[2][128];
  if (tid < 128) hbuf[0][tid] = 0;

  if (blockIdx.x < BB) {
    // ---------------- layer 0 (producer) ----------------
    const int b = blockIdx.x;
    uint4 whh[24];
    #pragma unroll
    for (int c = 0; c < 24; ++c) whh[c] = PHH0[c*1024 + tid];
    uint2 wih[12];
    #pragma unroll
    for (int r = 0; r < 12; ++r) wih[r] = PIH0[r*1024 + tid];
    const int j = 4*u + sl;
    const float br  = b_ih0[j]     + b_hh0[j];
    const float bz  = b_ih0[256+j] + b_hh0[256+j];
    const float bnx = b_ih0[512+j], bnh = b_hh0[512+j];
    const float* xrow = x + (size_t)b*TT*64 + 4*q;
    uint* h1row = h1g + (size_t)b*TT*128;
    float4 xf = *(const float4*)xrow;          // prefetch t=0
    float h_old = 0.f;
    __syncthreads();
    int cur = 0;
    #pragma unroll 1
    for (int t = 0; t < TT; ++t) {
      float4 xfn = xf;
      if (t+1 < TT) xfn = *(const float4*)(xrow + (t+1)*64);   // prefetch t+1
      uint xh0 = pack2(xf.x, xf.y), xh1 = pack2(xf.z, xf.w);
      uint4 ha = *((const uint4*)&hbuf[cur][0] + 2*q);
      uint4 hb = *((const uint4*)&hbuf[cur][0] + 2*q + 1);
      float aR[4], aZ[4], aNX[4], aNH[4];
      #pragma unroll
      for (int s = 0; s < 4; ++s) {
        aR[s]  = d16(whh[(0*4+s)*2+1], hb, d16(whh[(0*4+s)*2], ha, 0.f));
        aR[s]  = dot2(wih[0*4+s].y, xh1, dot2(wih[0*4+s].x, xh0, aR[s]));
        aZ[s]  = d16(whh[(1*4+s)*2+1], hb, d16(whh[(1*4+s)*2], ha, 0.f));
        aZ[s]  = dot2(wih[1*4+s].y, xh1, dot2(wih[1*4+s].x, xh0, aZ[s]));
        aNH[s] = d16(whh[(2*4+s)*2+1], hb, d16(whh[(2*4+s)*2], ha, 0.f));
        aNX[s] = dot2(wih[2*4+s].y, xh1, dot2(wih[2*4+s].x, xh0, 0.f));
      }
      #pragma unroll
      for (int s = 0; s < 4; ++s) {
        aR[s] = red16(aR[s]); aZ[s] = red16(aZ[s]);
        aNX[s] = red16(aNX[s]); aNH[s] = red16(aNH[s]);
      }
      float R  = pick4(aR[0],aR[1],aR[2],aR[3],sl);
      float Z  = pick4(aZ[0],aZ[1],aZ[2],aZ[3],sl);
      float NX = pick4(aNX[0],aNX[1],aNX[2],aNX[3],sl);
      float NH = pick4(aNH[0],aNH[1],aNH[2],aNH[3],sl);
      float r = sigf(R + br), z = sigf(Z + bz);
      float n = tanhf_(NX + bnx + r*(NH + bnh));
      float hn = z*(h_old - n) + n;
      h_old = hn;
      float hx = dpp_movf<0xB1>(hn);            // partner lane (q^1)
      uint v  = pack2(hn, hx);                  // valid on even q
      uint v2 = dpp_movu<0x4E>(v);              // lane q gets (q^2)'s pack
      if (q == 0) {
        uint2 hw; hw.x = v; hw.y = v2;
        *(uint2*)&hbuf[cur^1][2*u] = hw;
        *(uint2*)&h1row[t*128 + 2*u] = hw;
      }
      __syncthreads();
      if (tid == 0)
        __hip_atomic_store(&prog[b], t+1, __ATOMIC_RELEASE, __HIP_MEMORY_SCOPE_AGENT);
      xf = xfn; cur ^= 1;
    }
  } else {
    // ---------------- layer 1 (consumer) ----------------
    const int b = blockIdx.x - BB;
    uint4 whh[24], wih[24];
    #pragma unroll
    for (int c = 0; c < 24; ++c) whh[c] = PHH1[c*1024 + tid];
    #pragma unroll
    for (int c = 0; c < 24; ++c) wih[c] = PIH1[c*1024 + tid];
    const int j = 4*u + sl;
    const float br  = b_ih1[j]     + b_hh1[j];
    const float bz  = b_ih1[256+j] + b_hh1[256+j];
    const float bnx = b_ih1[512+j], bnh = b_hh1[512+j];
    const uint* xr = h1g + (size_t)b*TT*128 + 8*q;
    int* pr = prog + b;
    int seen = 0;
    while (seen < 1) {
      __builtin_amdgcn_s_sleep(8);
      seen = __hip_atomic_load(pr, __ATOMIC_RELAXED, __HIP_MEMORY_SCOPE_AGENT);
    }
    seen = __builtin_amdgcn_readfirstlane(seen);
    __builtin_amdgcn_fence(__ATOMIC_ACQUIRE, "agent");
    uint4 xa = *(const uint4*)(xr);
    uint4 xb = *(const uint4*)(xr + 4);
    bool havex = true;
    float h_old = 0.f;
    __syncthreads();
    int cur = 0;
    #pragma unroll 1
    for (int t = 0; t < TT; ++t) {
      if (!havex) {                               // ramp-only path
        while (seen < t+1) {
          __builtin_amdgcn_s_sleep(8);
          seen = __hip_atomic_load(pr, __ATOMIC_RELAXED, __HIP_MEMORY_SCOPE_AGENT);
        }
        seen = __builtin_amdgcn_readfirstlane(seen);
        __builtin_amdgcn_fence(__ATOMIC_ACQUIRE, "agent");
        xa = *(const uint4*)(xr + (size_t)t*128);
        xb = *(const uint4*)(xr + (size_t)t*128 + 4);
      }
      int pl = __hip_atomic_load(pr, __ATOMIC_RELAXED, __HIP_MEMORY_SCOPE_AGENT); // early, used late
      uint4 ha = *((const uint4*)&hbuf[cur][0] + 2*q);
      uint4 hb = *((const uint4*)&hbuf[cur][0] + 2*q + 1);
      float aR[4], aZ[4], aNX[4], aNH[4];
      #pragma unroll
      for (int s = 0; s < 4; ++s) {
        aR[s]  = d16(whh[(0*4+s)*2+1], hb, d16(whh[(0*4+s)*2], ha, 0.f));
        aR[s]  = d16(wih[(0*4+s)*2+1], xb, d16(wih[(0*4+s)*2], xa, aR[s]));
        aZ[s]  = d16(whh[(1*4+s)*2+1], hb, d16(whh[(1*4+s)*2], ha, 0.f));
        aZ[s]  = d16(wih[(1*4+s)*2+1], xb, d16(wih[(1*4+s)*2], xa, aZ[s]));
        aNH[s] = d16(whh[(2*4+s)*2+1], hb, d16(whh[(2*4+s)*2], ha, 0.f));
        aNX[s] = d16(wih[(2*4+s)*2+1], xb, d16(wih[(2*4+s)*2], xa, 0.f));
      }
      #pragma unroll
      for (int s = 0; s < 4; ++s) {
        aR[s] = red16(aR[s]); aZ[s] = red16(aZ[s]);
        aNX[s] = red16(aNX[s]); aNH[s] = red16(aNH[s]);
      }
      float R  = pick4(aR[0],aR[1],aR[2],aR[3],sl);
      float Z  = pick4(aZ[0],aZ[1],aZ[2],aZ[3],sl);
      float NX = pick4(aNX[0],aNX[1],aNX[2],aNX[3],sl);
      float NH = pick4(aNH[0],aNH[1],aNH[2],aNH[3],sl);
      float r = sigf(R + br), z = sigf(Z + bz);
      float n = tanhf_(NX + bnx + r*(NH + bnh));
      float hn = z*(h_old - n) + n;
      h_old = hn;
      float hx = dpp_movf<0xB1>(hn);
      uint v  = pack2(hn, hx);
      uint v2 = dpp_movu<0x4E>(v);
      if (q == 0) {
        uint2 hw; hw.x = v; hw.y = v2;
        *(uint2*)&hbuf[cur^1][2*u] = hw;
      }
      if (t == TT-1 && q < 4) h2o[b*256 + 4*u + q] = hn;
      pl = __builtin_amdgcn_readfirstlane(pl);
      if (pl > seen) { __builtin_amdgcn_fence(__ATOMIC_ACQUIRE, "agent"); seen = pl; }
      havex = false;
      if (t+1 < TT && seen >= t+2) {              // prefetch x_{t+1}
        xa = *(const uint4*)(xr + (size_t)(t+1)*128);
        xb = *(const uint4*)(xr + (size_t)(t+1)*128 + 4);
        havex = true;
      }
      __syncthreads();
      cur ^= 1;
    }
  }
}

// =================== MLP head ===================
__global__ __launch_bounds__(128) void mlp_kernel(
    const float* __restrict__ h2, const float* __restrict__ W1,
    const float* __restrict__ b1, const float* __restrict__ W2,
    const float* __restrict__ b2, float* __restrict__ out)
{
  __shared__ float hls[256];
  __shared__ float red[128];
  const int b = blockIdx.x, tid = threadIdx.x;
  if (tid < 64) ((float4*)hls)[tid] = ((const float4*)(h2 + (size_t)b*256))[tid];
  __syncthreads();
  float acc = b1[tid];
  const float4* w4 = (const float4*)(W1 + (size_t)tid*256);
  const float4* h4 = (const float4*)hls;
  #pragma unroll 8
  for (int k = 0; k < 64; ++k) {
    float4 w = w4[k]; float4 h = h4[k];
    acc = fmaf(w.x,h.x,acc); acc = fmaf(w.y,h.y,acc);
    acc = fmaf(w.z,h.z,acc); acc = fmaf(w.w,h.w,acc);
  }
  red[tid] = fmaxf(acc, 0.0f) * W2[tid];
  __syncthreads();
  for (int s = 64; s > 0; s >>= 1) {
    if (tid < s) red[tid] += red[tid + s];
    __syncthreads();
  }
  if (tid == 0) out[b] = red[0] + b2[0];
}

extern "C" void kernel_launch(void* const* d_in, const int* in_sizes, int n_in,
                              void* d_out, int out_size, void* d_ws, size_t ws_size,
                              hipStream_t stream)
{
  const float* x     = (const float*)d_in[0];
  const float* W_ih0 = (const float*)d_in[1];
  const float* W_hh0 = (const float*)d_in[2];
  const float* b_ih0 = (const float*)d_in[3];
  const float* b_hh0 = (const float*)d_in[4];
  const float* W_ih1 = (const float*)d_in[5];
  const float* W_hh1 = (const float*)d_in[6];
  const float* b_ih1 = (const float*)d_in[7];
  const float* b_hh1 = (const float*)d_in[8];
  const float* W1    = (const float*)d_in[9];
  const float* b1    = (const float*)d_in[10];
  const float* W2    = (const float*)d_in[11];
  const float* b2    = (const float*)d_in[12];

  char* ws = (char*)d_ws;
  uint*  PHH0 = (uint*)(ws + OFF_PHH0);
  uint*  PHH1 = (uint*)(ws + OFF_PHH1);
  uint*  PIH1 = (uint*)(ws + OFF_PIH1);
  uint*  PIH0 = (uint*)(ws + OFF_PIH0);
  int*   prog = (int*)(ws + OFF_PROG);
  float* H2O  = (float*)(ws + OFF_H2O);
  uint*  H1G  = (uint*)(ws + OFF_H1G);

  hipMemsetAsync(prog, 0, 512, stream);
  prep_kernel<<<1248, 256, 0, stream>>>(W_ih0, W_hh0, W_ih1, W_hh1,
                                        PHH0, PHH1, PIH1, PIH0);
  gru_fused<<<2*BB, 1024, 0, stream>>>(x,
                                       (const uint4*)PHH0, (const uint2*)PIH0,
                                       (const uint4*)PHH1, (const uint4*)PIH1,
                                       b_ih0, b_hh0, b_ih1, b_hh1,
                                       H1G, H2O, prog);
  mlp_kernel<<<BB, 128, 0, stream>>>(H2O, W1, b1, W2, b2, (float*)d_out);
}